// Round 1
// baseline (396.367 us; speedup 1.0000x reference)
//
#include <hip/hip_runtime.h>
#include <stdint.h>

#define M_DIM 8192
#define N_DIM 4096
#define K_DIM 4096
#define CBN   (K_DIM/8)   // 512 column groups per row

typedef __attribute__((ext_vector_type(8))) short bf16x8;
typedef __attribute__((ext_vector_type(8))) unsigned short u16x8;
typedef __attribute__((ext_vector_type(4))) float f32x4;

#define AS_GLOBAL(p) (const __attribute__((address_space(1))) void*)(p)
#define AS_LDS(p)    (__attribute__((address_space(3))) void*)(p)

static __device__ __forceinline__ unsigned short f2bf(float f) {
    union { float f; uint32_t u; } c; c.f = f;
    uint32_t u = c.u;
    return (unsigned short)((u + 0x7fffu + ((u >> 16) & 1u)) >> 16);
}

// ---------------------------------------------------------------------------
// Kernel 1: per (ob, cb) pick top-4 columns (of 8) by L1 mass over 64 rows.
// Pack the 4 selected column indices, in descending-score order (ties -> lower
// index, matching jax.lax.top_k), into nibbles of a u16.
// grid (64, 16), block 256. Thread t owns one column.
// ---------------------------------------------------------------------------
__global__ __launch_bounds__(256) void venom_sel(const float* __restrict__ W,
                                                 uint16_t* __restrict__ sel) {
    int t   = threadIdx.x;
    int ob  = blockIdx.x;
    int col = blockIdx.y * 256 + t;
    const float* p = W + (size_t)(ob * 64) * K_DIM + col;
    double s = 0.0;
    #pragma unroll 16
    for (int r = 0; r < 64; ++r) s += fabsf(p[(size_t)r * K_DIM]);

    int lane = t & 63;
    int base = lane & ~7;   // 8-lane group = one cb
    double sc[8];
    #pragma unroll
    for (int j = 0; j < 8; ++j) sc[j] = __shfl(s, base + j, 64);

    uint32_t packed = 0;
    #pragma unroll
    for (int c = 0; c < 8; ++c) {
        int rank = 0;
        #pragma unroll
        for (int j = 0; j < 8; ++j)
            rank += (sc[j] > sc[c]) || (sc[j] == sc[c] && j < c);
        if (rank < 4) packed |= (uint32_t)c << (4 * rank);
    }
    if ((lane & 7) == 0) {
        int cb = col >> 3;
        sel[ob * CBN + cb] = (uint16_t)packed;
    }
}

// ---------------------------------------------------------------------------
// Kernel 2: masked bf16 weight pack. One thread per (row, cb): keep top-2 of
// the 4 selected columns by |w| (ties -> earlier score-order position).
// ---------------------------------------------------------------------------
__global__ __launch_bounds__(256) void venom_pack(const float* __restrict__ W,
                                                  const uint16_t* __restrict__ sel,
                                                  unsigned short* __restrict__ Wb) {
    int gid = blockIdx.x * 256 + threadIdx.x;   // 4096*512 = 2M threads
    int o  = gid >> 9;
    int cb = gid & (CBN - 1);
    uint32_t pk = sel[(o >> 6) * CBN + cb];
    const float* p = W + (size_t)o * K_DIM + cb * 8;
    float4 a = *(const float4*)p;
    float4 b = *(const float4*)(p + 4);
    float w[8] = {a.x, a.y, a.z, a.w, b.x, b.y, b.z, b.w};

    int   c[4]; float v[4];
    #pragma unroll
    for (int pz = 0; pz < 4; ++pz) {
        c[pz] = (pk >> (4 * pz)) & 7;
        v[pz] = fabsf(w[c[pz]]);
    }
    uint32_t keep = 0;
    #pragma unroll
    for (int pz = 0; pz < 4; ++pz) {
        int cnt = 0;
        #pragma unroll
        for (int q = 0; q < 4; ++q)
            cnt += (v[q] > v[pz]) || (v[q] == v[pz] && q < pz);
        if (cnt < 2) keep |= 1u << c[pz];
    }
    u16x8 out;
    #pragma unroll
    for (int j = 0; j < 8; ++j)
        out[j] = f2bf(((keep >> j) & 1) ? w[j] : 0.0f);
    *(u16x8*)(Wb + (size_t)gid * 8) = out;
}

// ---------------------------------------------------------------------------
// Kernel 3: x f32 -> bf16 (RNE), 8 elements per thread.
// ---------------------------------------------------------------------------
__global__ __launch_bounds__(256) void xcvt(const float* __restrict__ X,
                                            unsigned short* __restrict__ Xb) {
    size_t gid = (size_t)blockIdx.x * 256 + threadIdx.x;
    const float4* p = (const float4*)X + gid * 2;
    float4 a = p[0], b = p[1];
    float w[8] = {a.x, a.y, a.z, a.w, b.x, b.y, b.z, b.w};
    u16x8 out;
    #pragma unroll
    for (int j = 0; j < 8; ++j) out[j] = f2bf(w[j]);
    *(u16x8*)(Xb + gid * 8) = out;
}

// ---------------------------------------------------------------------------
// Kernel 4: C[M][N] = A[M][K](bf16) * B[N][K](bf16)^T + bias, f32 out.
// m97 structure: 128x128 tile, BK=32, 4 waves (2x2) each 64x64,
// global_load_lds width 16, 16x16x32 bf16 MFMA, f32x4 acc[4][4]/wave.
// XOR swizzle kk' = kk ^ ((row>>1)&3) applied to the GLOBAL source column
// (LDS dest stays linear, rule #21) -> ds_read_b128 2-way conflict (free).
// ---------------------------------------------------------------------------
__global__ __launch_bounds__(256, 2) void gemm_bt(const unsigned short* __restrict__ A,
                                                  const unsigned short* __restrict__ B,
                                                  const float* __restrict__ bias,
                                                  float* __restrict__ C) {
    __shared__ __align__(16) unsigned short As[128 * 32];
    __shared__ __align__(16) unsigned short Bs[128 * 32];

    int t    = threadIdx.x;
    int wid  = t >> 6;
    int lane = t & 63;
    int l16  = lane & 15;
    int lk   = lane >> 4;

    // XCD-aware block swizzle (2048 blocks, 8 XCDs, 2048%8==0 -> bijective)
    int nbn = N_DIM / 128;                       // 32
    int bid = blockIdx.x;
    int swz = (bid & 7) * ((int)gridDim.x >> 3) + (bid >> 3);
    int bm  = swz / nbn;
    int bn  = swz % nbn;

    // staging: chunk i in [0,512) covers LDS bytes [i*16, i*16+16).
    // row = i>>2, stored k-slot kkp = i&3 holds global k-slot kkp^((row>>1)&3).
    int crow = t >> 2;                           // 0..63 (chunk set 0)
    int kkp  = t & 3;
    int gofs = (kkp ^ ((crow >> 1) & 3)) * 8;    // global column offset (elements)
    const unsigned short* agp0 = A + ((size_t)bm * 128 + crow) * K_DIM + gofs;
    const unsigned short* agp1 = agp0 + (size_t)64 * K_DIM;   // chunk set 1: row+64, same swizzle
    const unsigned short* bgp0 = B + ((size_t)bn * 128 + crow) * K_DIM + gofs;
    const unsigned short* bgp1 = bgp0 + (size_t)64 * K_DIM;

    char* aldsp0 = (char*)As + (t >> 6) * 1024;  // wave-uniform base, lane adds l*16
    char* aldsp1 = aldsp0 + 4096;
    char* bldsp0 = (char*)Bs + (t >> 6) * 1024;
    char* bldsp1 = bldsp0 + 4096;

    int wr = (wid >> 1) * 64;    // wave row offset in tile
    int wc = (wid & 1) * 64;     // wave col offset
    // read-side swizzle constant: row&.. bits below 16 come only from l16
    int koff = ((lk ^ ((l16 >> 1) & 3)) << 4);

    f32x4 acc[4][4] = {};

    for (int kt = 0; kt < K_DIM; kt += 32) {
        __syncthreads();
        __builtin_amdgcn_global_load_lds(AS_GLOBAL(agp0), AS_LDS(aldsp0), 16, 0, 0);
        __builtin_amdgcn_global_load_lds(AS_GLOBAL(agp1), AS_LDS(aldsp1), 16, 0, 0);
        __builtin_amdgcn_global_load_lds(AS_GLOBAL(bgp0), AS_LDS(bldsp0), 16, 0, 0);
        __builtin_amdgcn_global_load_lds(AS_GLOBAL(bgp1), AS_LDS(bldsp1), 16, 0, 0);
        agp0 += 32; agp1 += 32; bgp0 += 32; bgp1 += 32;
        asm volatile("s_waitcnt vmcnt(0)" ::: "memory");
        __syncthreads();

        bf16x8 af[4], bfr[4];
        #pragma unroll
        for (int i = 0; i < 4; ++i) {
            af[i]  = *(const bf16x8*)((const char*)As + (wr + i * 16 + l16) * 64 + koff);
            bfr[i] = *(const bf16x8*)((const char*)Bs + (wc + i * 16 + l16) * 64 + koff);
        }
        #pragma unroll
        for (int i = 0; i < 4; ++i)
            #pragma unroll
            for (int j = 0; j < 4; ++j)
                acc[i][j] = __builtin_amdgcn_mfma_f32_16x16x32_bf16(af[i], bfr[j], acc[i][j], 0, 0, 0);
    }

    // epilogue: C/D layout col = lane&15, row = (lane>>4)*4 + reg (m89/m91)
    int    colbase = bn * 128 + wc;
    size_t rowbase = (size_t)bm * 128 + wr + (lk << 2);
    #pragma unroll
    for (int j = 0; j < 4; ++j) {
        int col = colbase + j * 16 + l16;
        float bv = bias[col];
        #pragma unroll
        for (int i = 0; i < 4; ++i) {
            size_t r0 = rowbase + i * 16;
            #pragma unroll
            for (int rg = 0; rg < 4; ++rg)
                C[(r0 + rg) * N_DIM + col] = acc[i][j][rg] + bv;
        }
    }
}

extern "C" void kernel_launch(void* const* d_in, const int* in_sizes, int n_in,
                              void* d_out, int out_size, void* d_ws, size_t ws_size,
                              hipStream_t stream) {
    const float* x    = (const float*)d_in[0];
    const float* W    = (const float*)d_in[1];
    const float* bias = (const float*)d_in[2];
    float* out = (float*)d_out;

    char* ws = (char*)d_ws;
    unsigned short* xb  = (unsigned short*)ws;                                   // 64 MB
    unsigned short* wb  = (unsigned short*)(ws + (size_t)M_DIM * K_DIM * 2);     // 32 MB
    uint16_t*       sel = (uint16_t*)(ws + (size_t)M_DIM * K_DIM * 2
                                         + (size_t)N_DIM * K_DIM * 2);           // 64 KB

    venom_sel <<<dim3(64, 16), 256, 0, stream>>>(W, sel);
    venom_pack<<<dim3((N_DIM * CBN) / 256), 256, 0, stream>>>(W, sel, wb);
    xcvt      <<<dim3((M_DIM * K_DIM / 8) / 256), 256, 0, stream>>>(x, xb);
    gemm_bt   <<<dim3((M_DIM / 128) * (N_DIM / 128)), 256, 0, stream>>>(xb, wb, bias, out);
}

// Round 2
// 321.306 us; speedup vs baseline: 1.2336x; 1.2336x over previous
//
#include <hip/hip_runtime.h>
#include <stdint.h>

#define M_DIM 8192
#define N_DIM 4096
#define K_DIM 4096
#define CBN   (K_DIM/8)   // 512 column groups per row
#define NTILE (K_DIM/32)  // 128 K-tiles of BK=32

typedef __attribute__((ext_vector_type(8))) short bf16x8;
typedef __attribute__((ext_vector_type(8))) unsigned short u16x8;
typedef __attribute__((ext_vector_type(4))) float f32x4;

#define AS_GLOBAL(p) (const __attribute__((address_space(1))) void*)(p)
#define AS_LDS(p)    (__attribute__((address_space(3))) void*)(p)

static __device__ __forceinline__ unsigned short f2bf(float f) {
    union { float f; uint32_t u; } c; c.f = f;
    uint32_t u = c.u;
    return (unsigned short)((u + 0x7fffu + ((u >> 16) & 1u)) >> 16);
}

// ---------------------------------------------------------------------------
// Kernel 1: per (ob, cb) pick top-4 columns (of 8) by L1 mass over 64 rows.
// ---------------------------------------------------------------------------
__global__ __launch_bounds__(256) void venom_sel(const float* __restrict__ W,
                                                 uint16_t* __restrict__ sel) {
    int t   = threadIdx.x;
    int ob  = blockIdx.x;
    int col = blockIdx.y * 256 + t;
    const float* p = W + (size_t)(ob * 64) * K_DIM + col;
    double s = 0.0;
    #pragma unroll 16
    for (int r = 0; r < 64; ++r) s += fabsf(p[(size_t)r * K_DIM]);

    int lane = t & 63;
    int base = lane & ~7;
    double sc[8];
    #pragma unroll
    for (int j = 0; j < 8; ++j) sc[j] = __shfl(s, base + j, 64);

    uint32_t packed = 0;
    #pragma unroll
    for (int c = 0; c < 8; ++c) {
        int rank = 0;
        #pragma unroll
        for (int j = 0; j < 8; ++j)
            rank += (sc[j] > sc[c]) || (sc[j] == sc[c] && j < c);
        if (rank < 4) packed |= (uint32_t)c << (4 * rank);
    }
    if ((lane & 7) == 0) {
        int cb = col >> 3;
        sel[ob * CBN + cb] = (uint16_t)packed;
    }
}

// ---------------------------------------------------------------------------
// Kernel 2: masked bf16 weight pack (top-2 of selected 4 by |w|).
// ---------------------------------------------------------------------------
__global__ __launch_bounds__(256) void venom_pack(const float* __restrict__ W,
                                                  const uint16_t* __restrict__ sel,
                                                  unsigned short* __restrict__ Wb) {
    int gid = blockIdx.x * 256 + threadIdx.x;
    int o  = gid >> 9;
    int cb = gid & (CBN - 1);
    uint32_t pk = sel[(o >> 6) * CBN + cb];
    const float* p = W + (size_t)o * K_DIM + cb * 8;
    float4 a = *(const float4*)p;
    float4 b = *(const float4*)(p + 4);
    float w[8] = {a.x, a.y, a.z, a.w, b.x, b.y, b.z, b.w};

    int   c[4]; float v[4];
    #pragma unroll
    for (int pz = 0; pz < 4; ++pz) {
        c[pz] = (pk >> (4 * pz)) & 7;
        v[pz] = fabsf(w[c[pz]]);
    }
    uint32_t keep = 0;
    #pragma unroll
    for (int pz = 0; pz < 4; ++pz) {
        int cnt = 0;
        #pragma unroll
        for (int q = 0; q < 4; ++q)
            cnt += (v[q] > v[pz]) || (v[q] == v[pz] && q < pz);
        if (cnt < 2) keep |= 1u << c[pz];
    }
    u16x8 out;
    #pragma unroll
    for (int j = 0; j < 8; ++j)
        out[j] = f2bf(((keep >> j) & 1) ? w[j] : 0.0f);
    *(u16x8*)(Wb + (size_t)gid * 8) = out;
}

// ---------------------------------------------------------------------------
// Kernel 3: x f32 -> bf16 (RNE).
// ---------------------------------------------------------------------------
__global__ __launch_bounds__(256) void xcvt(const float* __restrict__ X,
                                            unsigned short* __restrict__ Xb) {
    size_t gid = (size_t)blockIdx.x * 256 + threadIdx.x;
    const float4* p = (const float4*)X + gid * 2;
    float4 a = p[0], b = p[1];
    float w[8] = {a.x, a.y, a.z, a.w, b.x, b.y, b.z, b.w};
    u16x8 out;
    #pragma unroll
    for (int j = 0; j < 8; ++j) out[j] = f2bf(w[j]);
    *(u16x8*)(Xb + gid * 8) = out;
}

// ---------------------------------------------------------------------------
// Kernel 4: 256x256-tile bf16 GEMM, C = A * B^T + bias.
// 8 waves (2Mx4N), BK=32, dbuf LDS 64KB, counted-vmcnt pipeline:
//   - each wave stages ONLY the half-tiles it consumes (per-wave vmcnt valid)
//   - loop: 2 phases x {ds_read, lgkmcnt(0), setprio(1), 16 MFMA, setprio(0)}
//   - boundary: s_barrier; stage tile t+2 into just-freed buf; vmcnt(4);
//     s_barrier  (never vmcnt(0) in steady state)
// XOR swizzle kchunk^=(row>>1)&3 on global source + read side (LDS linear).
// ---------------------------------------------------------------------------
__global__ __launch_bounds__(512, 2) void gemm256(const unsigned short* __restrict__ A,
                                                  const unsigned short* __restrict__ B,
                                                  const float* __restrict__ bias,
                                                  float* __restrict__ C) {
    __shared__ __align__(16) unsigned char smem[65536];  // A: 2x16KB @0, B: 2x16KB @32768

    int t    = threadIdx.x;
    int wid  = t >> 6;
    int lane = t & 63;
    int l16  = lane & 15;
    int lk   = lane >> 4;
    int wm   = wid >> 2;     // 0..1 : wave row-half of tile (128 rows)
    int wn   = wid & 3;      // 0..3 : wave col-quarter (64 cols)
    int qa   = wid & 3;      // quarter of A-half(wm) this wave stages
    int hb   = (wid >> 1) & 1;                 // B-half this wave consumes/stages
    int qb   = (wid & 1) | ((wid >> 2) << 1);  // quarter of B-half(hb)

    // XCD-aware bijective swizzle (512 blocks % 8 == 0)
    int bid = blockIdx.x;
    int swz = (bid & 7) * ((int)gridDim.x >> 3) + (bid >> 3);
    int bm  = swz >> 4;      // 0..31
    int bn  = swz & 15;      // 0..15

    // staging: chunk c_local = q*128 + j*64 + lane -> row=c>>2, phys slot=lane&3
    // logical kchunk = (lane&3) ^ ((row>>1)&3), (row>>1)&3 == (lane>>3)&3
    int gofs = (((lane & 3) ^ ((lane >> 3) & 3)) << 3);  // element offset in BK
    const unsigned short* ag = A + (size_t)(bm * 256 + wm * 128 + qa * 32 + (lane >> 2)) * K_DIM + gofs;
    const unsigned short* bg = B + (size_t)(bn * 256 + hb * 128 + qb * 32 + (lane >> 2)) * K_DIM + gofs;

    char* aw0 = (char*)smem + wm * 8192 + qa * 2048;           // wave-uniform LDS dests
    char* bw0 = (char*)smem + 32768 + hb * 8192 + qb * 2048;

    auto stage = [&](int curoff) {
        __builtin_amdgcn_global_load_lds(AS_GLOBAL(ag),                        AS_LDS(aw0 + curoff),        16, 0, 0);
        __builtin_amdgcn_global_load_lds(AS_GLOBAL(ag + (size_t)16 * K_DIM),   AS_LDS(aw0 + curoff + 1024), 16, 0, 0);
        __builtin_amdgcn_global_load_lds(AS_GLOBAL(bg),                        AS_LDS(bw0 + curoff),        16, 0, 0);
        __builtin_amdgcn_global_load_lds(AS_GLOBAL(bg + (size_t)16 * K_DIM),   AS_LDS(bw0 + curoff + 1024), 16, 0, 0);
        ag += 32; bg += 32;
    };

    // read-side swizzle: lane reads row (..+l16), slot lk -> phys slot lk^((l16>>1)&3)
    int koff = ((lk ^ ((l16 >> 1) & 3)) << 4);
    const char* ard = (const char*)smem + wm * 8192 + l16 * 64 + koff;
    const char* brd = (const char*)smem + 32768 + wn * 4096 + l16 * 64 + koff;

    f32x4 acc[8][4] = {};

    // prologue: tiles 0 and 1
    stage(0);
    stage(16384);
    asm volatile("s_waitcnt vmcnt(4)" ::: "memory");
    __builtin_amdgcn_sched_barrier(0);
    __builtin_amdgcn_s_barrier();
    __builtin_amdgcn_sched_barrier(0);

    for (int kt = 0; kt < NTILE; ++kt) {
        int curoff = (kt & 1) << 14;
        const char* ab = ard + curoff;
        const char* bb = brd + curoff;

        bf16x8 bfr[4], af[4];
        // ---- phase 0: rowhalf 0 ----
        #pragma unroll
        for (int g = 0; g < 4; ++g) bfr[g] = *(const bf16x8*)(bb + g * 1024);
        #pragma unroll
        for (int i = 0; i < 4; ++i) af[i] = *(const bf16x8*)(ab + i * 1024);
        asm volatile("s_waitcnt lgkmcnt(0)" ::: "memory");
        __builtin_amdgcn_sched_barrier(0);
        __builtin_amdgcn_s_setprio(1);
        #pragma unroll
        for (int i = 0; i < 4; ++i)
            #pragma unroll
            for (int g = 0; g < 4; ++g)
                acc[i][g] = __builtin_amdgcn_mfma_f32_16x16x32_bf16(af[i], bfr[g], acc[i][g], 0, 0, 0);
        __builtin_amdgcn_s_setprio(0);
        __builtin_amdgcn_sched_barrier(0);

        // ---- phase 1: rowhalf 1 (reuse bfr) ----
        #pragma unroll
        for (int i = 0; i < 4; ++i) af[i] = *(const bf16x8*)(ab + 4096 + i * 1024);
        asm volatile("s_waitcnt lgkmcnt(0)" ::: "memory");
        __builtin_amdgcn_sched_barrier(0);
        __builtin_amdgcn_s_setprio(1);
        #pragma unroll
        for (int i = 0; i < 4; ++i)
            #pragma unroll
            for (int g = 0; g < 4; ++g)
                acc[4 + i][g] = __builtin_amdgcn_mfma_f32_16x16x32_bf16(af[i], bfr[g], acc[4 + i][g], 0, 0, 0);
        __builtin_amdgcn_s_setprio(0);
        __builtin_amdgcn_sched_barrier(0);

        // ---- boundary ----
        __builtin_amdgcn_s_barrier();          // all waves done reading buf[cur]
        __builtin_amdgcn_sched_barrier(0);
        if (kt + 2 < NTILE) {
            stage(curoff);                     // tile kt+2 into just-freed buffer
            __builtin_amdgcn_sched_barrier(0);
            asm volatile("s_waitcnt vmcnt(4)" ::: "memory");   // tile kt+1 landed (mine)
        } else {
            asm volatile("s_waitcnt vmcnt(0)" ::: "memory");   // epilogue drain
        }
        __builtin_amdgcn_sched_barrier(0);
        __builtin_amdgcn_s_barrier();          // tile kt+1 visible to all waves
        __builtin_amdgcn_sched_barrier(0);
    }

    // epilogue: C/D layout col = lane&15, row = (lane>>4)*4 + reg
    int    colb = bn * 256 + wn * 64;
    size_t rowb = (size_t)bm * 256 + wm * 128 + (lk << 2);
    #pragma unroll
    for (int g = 0; g < 4; ++g) {
        int col = colb + g * 16 + l16;
        float bv = bias[col];
        #pragma unroll
        for (int f = 0; f < 8; ++f) {
            size_t r0 = rowb + f * 16;
            #pragma unroll
            for (int rg = 0; rg < 4; ++rg)
                C[(r0 + rg) * N_DIM + col] = acc[f][g][rg] + bv;
        }
    }
}

extern "C" void kernel_launch(void* const* d_in, const int* in_sizes, int n_in,
                              void* d_out, int out_size, void* d_ws, size_t ws_size,
                              hipStream_t stream) {
    const float* x    = (const float*)d_in[0];
    const float* W    = (const float*)d_in[1];
    const float* bias = (const float*)d_in[2];
    float* out = (float*)d_out;

    char* ws = (char*)d_ws;
    unsigned short* xb  = (unsigned short*)ws;                                   // 64 MB
    unsigned short* wb  = (unsigned short*)(ws + (size_t)M_DIM * K_DIM * 2);     // 32 MB
    uint16_t*       sel = (uint16_t*)(ws + (size_t)M_DIM * K_DIM * 2
                                         + (size_t)N_DIM * K_DIM * 2);           // 64 KB

    venom_sel <<<dim3(64, 16), 256, 0, stream>>>(W, sel);
    venom_pack<<<dim3((N_DIM * CBN) / 256), 256, 0, stream>>>(W, sel, wb);
    xcvt      <<<dim3((M_DIM * K_DIM / 8) / 256), 256, 0, stream>>>(x, xb);
    gemm256   <<<dim3((M_DIM / 256) * (N_DIM / 256)), 512, 0, stream>>>(xb, wb, bias, out);
}

// Round 3
// 290.705 us; speedup vs baseline: 1.3635x; 1.1053x over previous
//
#include <hip/hip_runtime.h>
#include <stdint.h>

#define M_DIM 8192
#define N_DIM 4096
#define K_DIM 4096
#define CBN   (K_DIM/8)   // 512 column groups per row
#define ITERS 32          // 64 K-tiles of BK=64, 2 per iteration

typedef __attribute__((ext_vector_type(8))) short bf16x8;
typedef __attribute__((ext_vector_type(8))) unsigned short u16x8;
typedef __attribute__((ext_vector_type(4))) float f32x4;

#define AS_GLOBAL(p) (const __attribute__((address_space(1))) void*)(p)
#define AS_LDS(p)    (__attribute__((address_space(3))) void*)(p)

static __device__ __forceinline__ unsigned short f2bf(float f) {
    union { float f; uint32_t u; } c; c.f = f;
    uint32_t u = c.u;
    return (unsigned short)((u + 0x7fffu + ((u >> 16) & 1u)) >> 16);
}

// ---------------------------------------------------------------------------
// Kernel 1: per (ob, cb) pick top-4 columns (of 8) by L1 mass over 64 rows.
// ---------------------------------------------------------------------------
__global__ __launch_bounds__(256) void venom_sel(const float* __restrict__ W,
                                                 uint16_t* __restrict__ sel) {
    int t   = threadIdx.x;
    int ob  = blockIdx.x;
    int col = blockIdx.y * 256 + t;
    const float* p = W + (size_t)(ob * 64) * K_DIM + col;
    double s = 0.0;
    #pragma unroll 16
    for (int r = 0; r < 64; ++r) s += fabsf(p[(size_t)r * K_DIM]);

    int lane = t & 63;
    int base = lane & ~7;
    double sc[8];
    #pragma unroll
    for (int j = 0; j < 8; ++j) sc[j] = __shfl(s, base + j, 64);

    uint32_t packed = 0;
    #pragma unroll
    for (int c = 0; c < 8; ++c) {
        int rank = 0;
        #pragma unroll
        for (int j = 0; j < 8; ++j)
            rank += (sc[j] > sc[c]) || (sc[j] == sc[c] && j < c);
        if (rank < 4) packed |= (uint32_t)c << (4 * rank);
    }
    if ((lane & 7) == 0) {
        int cb = col >> 3;
        sel[ob * CBN + cb] = (uint16_t)packed;
    }
}

// ---------------------------------------------------------------------------
// Kernel 2: masked bf16 weight pack (top-2 of selected 4 by |w|).
// ---------------------------------------------------------------------------
__global__ __launch_bounds__(256) void venom_pack(const float* __restrict__ W,
                                                  const uint16_t* __restrict__ sel,
                                                  unsigned short* __restrict__ Wb) {
    int gid = blockIdx.x * 256 + threadIdx.x;
    int o  = gid >> 9;
    int cb = gid & (CBN - 1);
    uint32_t pk = sel[(o >> 6) * CBN + cb];
    const float* p = W + (size_t)o * K_DIM + cb * 8;
    float4 a = *(const float4*)p;
    float4 b = *(const float4*)(p + 4);
    float w[8] = {a.x, a.y, a.z, a.w, b.x, b.y, b.z, b.w};

    int   c[4]; float v[4];
    #pragma unroll
    for (int pz = 0; pz < 4; ++pz) {
        c[pz] = (pk >> (4 * pz)) & 7;
        v[pz] = fabsf(w[c[pz]]);
    }
    uint32_t keep = 0;
    #pragma unroll
    for (int pz = 0; pz < 4; ++pz) {
        int cnt = 0;
        #pragma unroll
        for (int q = 0; q < 4; ++q)
            cnt += (v[q] > v[pz]) || (v[q] == v[pz] && q < pz);
        if (cnt < 2) keep |= 1u << c[pz];
    }
    u16x8 out;
    #pragma unroll
    for (int j = 0; j < 8; ++j)
        out[j] = f2bf(((keep >> j) & 1) ? w[j] : 0.0f);
    *(u16x8*)(Wb + (size_t)gid * 8) = out;
}

// ---------------------------------------------------------------------------
// Kernel 3: x f32 -> bf16 (RNE).
// ---------------------------------------------------------------------------
__global__ __launch_bounds__(256) void xcvt(const float* __restrict__ X,
                                            unsigned short* __restrict__ Xb) {
    size_t gid = (size_t)blockIdx.x * 256 + threadIdx.x;
    const float4* p = (const float4*)X + gid * 2;
    float4 a = p[0], b = p[1];
    float w[8] = {a.x, a.y, a.z, a.w, b.x, b.y, b.z, b.w};
    u16x8 out;
    #pragma unroll
    for (int j = 0; j < 8; ++j) out[j] = f2bf(w[j]);
    *(u16x8*)(Xb + gid * 8) = out;
}

// ---------------------------------------------------------------------------
// Kernel 4: 256x256 bf16 GEMM, 8-phase counted-vmcnt schedule (m201 template).
// BK=64 (2 K-slices of 32), 2 K-tiles per iteration, dbuf LDS 128KB.
// Half-tile = one K-slice of A or B (256x32 bf16 = 16KB), staged 1 per phase,
// consumed 4 phases later. vmcnt(4) checkpoints at even phases (never 0 in
// steady state). XOR swizzle chunk^=(row>>1)&3 on global source + read side.
// Hazard ledger: region overwritten at phase p was last read at p-4 (behind
// >=2 barriers); region read at phase p was vmcnt-covered at p-1's checkpoint.
// ---------------------------------------------------------------------------
__global__ __launch_bounds__(512, 2) void gemm256(const unsigned short* __restrict__ A,
                                                  const unsigned short* __restrict__ B,
                                                  const float* __restrict__ bias,
                                                  float* __restrict__ C) {
    __shared__ __align__(16) unsigned char smem[131072]; // A:[0,64K) B:[64K,128K)

    int t    = threadIdx.x;
    int wid  = t >> 6;
    int lane = t & 63;
    int l16  = lane & 15;
    int lk   = lane >> 4;
    int wm   = wid >> 2;     // 0..1 : wave row-half (128 rows)
    int wn   = wid & 3;      // 0..3 : wave col-quarter (64 cols)

    // XCD-aware bijective swizzle (512 blocks % 8 == 0)
    int bid = blockIdx.x;
    int swz = (bid & 7) * ((int)gridDim.x >> 3) + (bid >> 3);
    int bm  = swz >> 4;      // 0..31
    int bn  = swz & 15;      // 0..15

    // staging: thread t covers row r=t>>2 (and r+128), phys chunk t&3 holds
    // logical chunk (t&3)^((r>>1)&3) = (t&3)^((t>>3)&3)
    int gch = ((t & 3) ^ ((t >> 3) & 3)) * 8;
    const unsigned short* agbase = A + (size_t)(bm * 256 + (t >> 2)) * K_DIM + gch;
    const unsigned short* bgbase = B + (size_t)(bn * 256 + (t >> 2)) * K_DIM + gch;

    // stage one half-tile (16KB): 2 global_load_lds, wave-uniform LDS dest
    auto stageA = [&](int tile, int ks, int buf) {
        const unsigned short* gb = agbase + tile * 64 + ks * 32;
        char* ld = (char*)smem + buf * 32768 + ks * 16384 + wid * 1024;
        __builtin_amdgcn_global_load_lds(AS_GLOBAL(gb), AS_LDS(ld), 16, 0, 0);
        __builtin_amdgcn_global_load_lds(AS_GLOBAL(gb + (size_t)128 * K_DIM), AS_LDS(ld + 8192), 16, 0, 0);
    };
    auto stageB = [&](int tile, int ks, int buf) {
        const unsigned short* gb = bgbase + tile * 64 + ks * 32;
        char* ld = (char*)smem + 65536 + buf * 32768 + ks * 16384 + wid * 1024;
        __builtin_amdgcn_global_load_lds(AS_GLOBAL(gb), AS_LDS(ld), 16, 0, 0);
        __builtin_amdgcn_global_load_lds(AS_GLOBAL(gb + (size_t)128 * K_DIM), AS_LDS(ld + 8192), 16, 0, 0);
    };

    // read-side: row R = base+l16, k-chunk lk -> phys chunk lk^((l16>>1)&3)
    int koff = ((lk ^ ((l16 >> 1) & 3)) << 4);
    const char* ardb = (const char*)smem + (wm * 128 + l16) * 64 + koff;
    const char* brdb = (const char*)smem + 65536 + (wn * 64 + l16) * 64 + koff;

    f32x4 acc[8][4] = {};
    bf16x8 af[4], bfr[4];

#define PH_READS(BUF, KS, MH, LOADB)                                               \
    if (LOADB) {                                                                   \
        _Pragma("unroll")                                                          \
        for (int g = 0; g < 4; ++g)                                                \
            bfr[g] = *(const bf16x8*)(brdb + (BUF)*32768 + (KS)*16384 + g * 1024); \
    }                                                                              \
    _Pragma("unroll")                                                              \
    for (int i = 0; i < 4; ++i)                                                    \
        af[i] = *(const bf16x8*)(ardb + (BUF)*32768 + (KS)*16384 + ((MH)*4 + i) * 1024);

#define PH_EXEC(MH)                                                                \
    __builtin_amdgcn_s_barrier();                                                  \
    asm volatile("s_waitcnt lgkmcnt(0)" ::: "memory");                             \
    __builtin_amdgcn_sched_barrier(0);                                             \
    __builtin_amdgcn_s_setprio(1);                                                 \
    _Pragma("unroll")                                                              \
    for (int i = 0; i < 4; ++i)                                                    \
        _Pragma("unroll")                                                          \
        for (int g = 0; g < 4; ++g)                                                \
            acc[(MH)*4 + i][g] = __builtin_amdgcn_mfma_f32_16x16x32_bf16(af[i], bfr[g], acc[(MH)*4 + i][g], 0, 0, 0); \
    __builtin_amdgcn_s_setprio(0);                                                 \
    __builtin_amdgcn_sched_barrier(0);

#define PH_CLOSE()                                                                 \
    __builtin_amdgcn_s_barrier();                                                  \
    __builtin_amdgcn_sched_barrier(0);

#define CKPT4()  { asm volatile("s_waitcnt vmcnt(4)" ::: "memory"); __builtin_amdgcn_sched_barrier(0); }
#define CKPT0()  { asm volatile("s_waitcnt vmcnt(0)" ::: "memory"); __builtin_amdgcn_sched_barrier(0); }

    // prologue: tile 0's four halves; wait ks0 landed (ks1 stays in flight)
    stageA(0, 0, 0); stageB(0, 0, 0);
    stageA(0, 1, 0); stageB(0, 1, 0);
    CKPT4();
    __builtin_amdgcn_s_barrier();
    __builtin_amdgcn_sched_barrier(0);

    for (int it = 0; it < ITERS; ++it) {
        int tn = 2 * it + 1;          // odd tile (staged P1-P4, computed P5-P8)
        int tp = 2 * it + 2;          // next even tile (staged P5-P8)
        bool more = (it < ITERS - 1);

        // P1: tile 2t, ks0, Mh0
        PH_READS(0, 0, 0, 1)
        stageA(tn, 0, 1);
        PH_EXEC(0)
        PH_CLOSE()
        // P2: ks0, Mh1
        PH_READS(0, 0, 1, 0)
        stageB(tn, 0, 1);
        PH_EXEC(1)
        CKPT4()
        PH_CLOSE()
        // P3: ks1, Mh0
        PH_READS(0, 1, 0, 1)
        stageA(tn, 1, 1);
        PH_EXEC(0)
        PH_CLOSE()
        // P4: ks1, Mh1
        PH_READS(0, 1, 1, 0)
        stageB(tn, 1, 1);
        PH_EXEC(1)
        CKPT4()
        PH_CLOSE()
        // P5: tile 2t+1, ks0, Mh0
        PH_READS(1, 0, 0, 1)
        if (more) stageA(tp, 0, 0);
        PH_EXEC(0)
        PH_CLOSE()
        // P6: ks0, Mh1
        PH_READS(1, 0, 1, 0)
        if (more) stageB(tp, 0, 0);
        PH_EXEC(1)
        if (more) { CKPT4() } else { CKPT0() }
        PH_CLOSE()
        // P7: ks1, Mh0
        PH_READS(1, 1, 0, 1)
        if (more) stageA(tp, 1, 0);
        PH_EXEC(0)
        PH_CLOSE()
        // P8: ks1, Mh1
        PH_READS(1, 1, 1, 0)
        if (more) stageB(tp, 1, 0);
        PH_EXEC(1)
        if (more) { CKPT4() }
        PH_CLOSE()
    }

    // epilogue: C/D layout col = lane&15, row = (lane>>4)*4 + reg
    int    colb = bn * 256 + wn * 64;
    size_t rowb = (size_t)bm * 256 + wm * 128 + (lk << 2);
    #pragma unroll
    for (int g = 0; g < 4; ++g) {
        int col = colb + g * 16 + l16;
        float bv = bias[col];
        #pragma unroll
        for (int f = 0; f < 8; ++f) {
            size_t r0 = rowb + f * 16;
            #pragma unroll
            for (int rg = 0; rg < 4; ++rg)
                C[(r0 + rg) * N_DIM + col] = acc[f][g][rg] + bv;
        }
    }
}

extern "C" void kernel_launch(void* const* d_in, const int* in_sizes, int n_in,
                              void* d_out, int out_size, void* d_ws, size_t ws_size,
                              hipStream_t stream) {
    const float* x    = (const float*)d_in[0];
    const float* W    = (const float*)d_in[1];
    const float* bias = (const float*)d_in[2];
    float* out = (float*)d_out;

    char* ws = (char*)d_ws;
    unsigned short* xb  = (unsigned short*)ws;                                   // 64 MB
    unsigned short* wb  = (unsigned short*)(ws + (size_t)M_DIM * K_DIM * 2);     // 32 MB
    uint16_t*       sel = (uint16_t*)(ws + (size_t)M_DIM * K_DIM * 2
                                         + (size_t)N_DIM * K_DIM * 2);           // 64 KB

    venom_sel <<<dim3(64, 16), 256, 0, stream>>>(W, sel);
    venom_pack<<<dim3((N_DIM * CBN) / 256), 256, 0, stream>>>(W, sel, wb);
    xcvt      <<<dim3((M_DIM * K_DIM / 8) / 256), 256, 0, stream>>>(x, xb);
    gemm256   <<<dim3((M_DIM / 256) * (N_DIM / 256)), 512, 0, stream>>>(xb, wb, bias, out);
}